// Round 3
// baseline (218.604 us; speedup 1.0000x reference)
//
#include <hip/hip_runtime.h>

// F0=64, F1=128, F2=64. n<=65536.
// Direct slotted-per-node CSR: slot[d*64 + p] holds u16 src ids (p from a
// global atomic cursor). In-degree is ~Poisson(16); 64 slots never overflow
// on this input (clamped defensively).
// Pipeline: memset(deg/cur, 400KB) -> scatter_edges (+weight preconvert in
//           spare block) -> prep2 (norms + h*norm bf16 cast, streaming) ->
//           gather24(xb->agg1b bf16) -> gemm12_mfma (both layers, H in LDS)
//           -> gather24(y2b->out f32,+b2)

#define SLOTLOG 6
#define SLOT (1 << SLOTLOG)

typedef __attribute__((ext_vector_type(8))) short bf16x8;
typedef __attribute__((ext_vector_type(4))) float f32x4;

__device__ inline unsigned short f2bf(float f) {
    unsigned int u = __float_as_uint(f);
    unsigned int r = (u + 0x7FFFu + ((u >> 16) & 1u)) >> 16;  // RNE
    return (unsigned short)r;
}
__device__ inline float bf2f_lo(unsigned int u) { return __uint_as_float(u << 16); }
__device__ inline float bf2f_hi(unsigned int u) { return __uint_as_float(u & 0xFFFF0000u); }

// One streaming pass over edges. Per edge: src-degree hist atomic (no return),
// dst cursor atomic (returns slot position), u16 scattered store.
// LAST block instead pre-converts W1/W2 into padded bf16 images so gemm12
// stages with pure vec copies.
__global__ __launch_bounds__(256) void scatter_edges(const int* __restrict__ src,
        const int* __restrict__ dst, int* __restrict__ deg_out,
        int* __restrict__ cur_in, unsigned short* __restrict__ slot, int n_edges,
        const float* __restrict__ W1, const float* __restrict__ W2,
        unsigned short* __restrict__ w1t_g, unsigned short* __restrict__ w2t_g) {
    if (blockIdx.x == gridDim.x - 1) {
        for (int i = threadIdx.x; i < 8192; i += 256) {   // W1[64][128] -> [n][k] pad 72
            int k = i >> 7, nn = i & 127;
            w1t_g[nn * 72 + k] = f2bf(W1[i]);
        }
        for (int i = threadIdx.x; i < 8192; i += 256) {   // W2[128][64] -> [n][k] pad 136
            int k = i >> 6, nn = i & 63;
            w2t_g[nn * 136 + k] = f2bf(W2[i]);
        }
        return;
    }
    int e0 = (blockIdx.x * 256 + threadIdx.x) * 4;
    if (e0 + 3 < n_edges) {
        const int4 s4 = *(const int4*)(src + e0);
        const int4 d4 = *(const int4*)(dst + e0);
        // degree hist (no return value -> fire-and-forget atomics)
        atomicAdd(&deg_out[s4.x], 1);
        atomicAdd(&deg_out[s4.y], 1);
        atomicAdd(&deg_out[s4.z], 1);
        atomicAdd(&deg_out[s4.w], 1);
        // four independent cursor chains for ILP
        int p0 = atomicAdd(&cur_in[d4.x], 1);
        int p1 = atomicAdd(&cur_in[d4.y], 1);
        int p2 = atomicAdd(&cur_in[d4.z], 1);
        int p3 = atomicAdd(&cur_in[d4.w], 1);
        if (p0 < SLOT) slot[((size_t)d4.x << SLOTLOG) + p0] = (unsigned short)s4.x;
        if (p1 < SLOT) slot[((size_t)d4.y << SLOTLOG) + p1] = (unsigned short)s4.y;
        if (p2 < SLOT) slot[((size_t)d4.z << SLOTLOG) + p2] = (unsigned short)s4.z;
        if (p3 < SLOT) slot[((size_t)d4.w << SLOTLOG) + p3] = (unsigned short)s4.w;
    } else {
        for (int j = 0; j < 4; ++j) {
            int e = e0 + j;
            if (e < n_edges) {
                int s = src[e], d = dst[e];
                atomicAdd(&deg_out[s], 1);
                int p = atomicAdd(&cur_in[d], 1);
                if (p < SLOT) slot[((size_t)d << SLOTLOG) + p] = (unsigned short)s;
            }
        }
    }
}

// One block per 128 nodes: norms from deg arrays (coalesced), then
// xb = bf16(h * norm_src) streaming cast.
__global__ __launch_bounds__(256) void prep2(const float* __restrict__ h,
        const int* __restrict__ deg_out, const int* __restrict__ cur_in,
        float* __restrict__ norm_src, float* __restrict__ norm_dst,
        unsigned short* __restrict__ xb, int n) {
    __shared__ float nrm[128];
    const int b = blockIdx.x;
    const int tid = threadIdx.x;
    const int base = b << 7;
    if (tid < 128) {
        int node = base + tid;
        if (node < n) {
            int c = deg_out[node]; if (c < 1) c = 1;
            float s = 1.0f / sqrtf((float)c);
            nrm[tid] = s;
            norm_src[node] = s;
            int ci = cur_in[node]; if (ci < 1) ci = 1;
            norm_dst[node] = 1.0f / sqrtf((float)ci);
        }
    }
    __syncthreads();
    for (int t = tid; t < 128 * 16; t += 256) {
        int r = t >> 4, c4 = (t & 15) << 2;
        int node = base + r;
        if (node < n) {
            float s = nrm[r];
            float4 v = *(const float4*)(h + (size_t)node * 64 + c4);
            ushort4 o;
            o.x = f2bf(v.x * s); o.y = f2bf(v.y * s);
            o.z = f2bf(v.z * s); o.w = f2bf(v.w * s);
            *(ushort4*)(xb + (size_t)node * 64 + c4) = o;
        }
    }
}

// One wave per dst node. 8 lanes x bf16x8 (16B dwordx4) cover the 64-wide row;
// 8 lane-groups x unroll 3 -> 24 edges in flight per round.
// f32 accumulate, 3-level shfl_xor reduce; writes bf16 row (mode 1) or f32
// row +bias (mode 0). Edge ranges are [node*64, +deg_in).
__global__ __launch_bounds__(256) void gather24(const unsigned short* __restrict__ xb,
        const unsigned short* __restrict__ slot, const int* __restrict__ deg_in,
        const float* __restrict__ nrm, const float* __restrict__ bias,
        void* __restrict__ outp, int write_bf, int n_nodes) {
    int node = blockIdx.x * 4 + (threadIdx.x >> 6);
    if (node >= n_nodes) return;
    int lane = threadIdx.x & 63;
    int g  = lane >> 3;         // edge slot 0..7
    int c8 = (lane & 7) * 8;    // column base
    int dg = deg_in[node]; if (dg > SLOT) dg = SLOT;
    int a0 = node << SLOTLOG;
    int a1 = a0 + dg;
    float acc[8];
    #pragma unroll
    for (int j = 0; j < 8; ++j) acc[j] = 0.f;
    for (int base = a0; base < a1; base += 24) {
        #pragma unroll
        for (int u = 0; u < 3; ++u) {
            int ei = base + u * 8 + g;
            int idx = ei < a1 ? ei : a1 - 1;
            float msk = ei < a1 ? 1.0f : 0.0f;
            int s = slot[idx];
            const uint4 v = *(const uint4*)(xb + (size_t)s * 64 + c8);
            acc[0] = fmaf(bf2f_lo(v.x), msk, acc[0]);
            acc[1] = fmaf(bf2f_hi(v.x), msk, acc[1]);
            acc[2] = fmaf(bf2f_lo(v.y), msk, acc[2]);
            acc[3] = fmaf(bf2f_hi(v.y), msk, acc[3]);
            acc[4] = fmaf(bf2f_lo(v.z), msk, acc[4]);
            acc[5] = fmaf(bf2f_hi(v.z), msk, acc[5]);
            acc[6] = fmaf(bf2f_lo(v.w), msk, acc[6]);
            acc[7] = fmaf(bf2f_hi(v.w), msk, acc[7]);
        }
    }
    #pragma unroll
    for (int off = 8; off < 64; off <<= 1) {
        #pragma unroll
        for (int j = 0; j < 8; ++j) acc[j] += __shfl_xor(acc[j], off, 64);
    }
    if (g == 0) {
        float s = nrm[node];
        float r[8];
        #pragma unroll
        for (int j = 0; j < 8; ++j) r[j] = acc[j] * s;
        if (write_bf) {
            unsigned short rb[8];
            #pragma unroll
            for (int j = 0; j < 8; ++j) rb[j] = f2bf(r[j]);
            unsigned short* o = (unsigned short*)outp + (size_t)node * 64 + c8;
            *(ushort4*)(o)     = make_ushort4(rb[0], rb[1], rb[2], rb[3]);
            *(ushort4*)(o + 4) = make_ushort4(rb[4], rb[5], rb[6], rb[7]);
        } else {
            if (bias) {
                #pragma unroll
                for (int j = 0; j < 8; ++j) r[j] += bias[c8 + j];
            }
            float* o = (float*)outp + (size_t)node * 64 + c8;
            *(float4*)(o)     = make_float4(r[0], r[1], r[2], r[3]);
            *(float4*)(o + 4) = make_float4(r[4], r[5], r[6], r[7]);
        }
    }
}

// MFMA fused both layers per 64-node tile. 4 waves, wave w owns nodes
// m0+w*16..+15.  Layouts (verified per guide m89/m91/m120):
//   A-frag  lane l: A[m = l&15][k = (l>>4)*8 + j]     (bf16x8, 16B/lane)
//   B-frag  lane l: B[k = (l>>4)*8 + j][n = l&15]
//   C/D     lane l reg r: D[m = (l>>4)*4 + r][n = l&15]
// W1t/W2t images are pre-built in global (scatter_edges spare block); staging
// here is pure uint4 LDS copy. H tile (layer-1 out) goes through LDS
// (C-layout -> A-layout transform).
__global__ __launch_bounds__(256) void gemm12(const unsigned short* __restrict__ Ab,
        const unsigned short* __restrict__ w1t_g, const float* __restrict__ b1,
        const float* __restrict__ norm, const unsigned short* __restrict__ w2t_g,
        unsigned short* __restrict__ y2b, int n) {
    __shared__ __align__(16) unsigned short W1t[128 * 72];   // [n][k] pad 72 (2-way, free)
    __shared__ __align__(16) unsigned short W2t[64 * 136];   // [n][k] pad 136
    __shared__ __align__(16) unsigned short Hs[64 * 136];    // [m][k] pad 136
    __shared__ float b1s[128];
    const int tid = threadIdx.x;

    {   // stage pre-built weight images: 1152 + 1088 uint4
        const uint4* s1 = (const uint4*)w1t_g;
        uint4* d1 = (uint4*)W1t;
        for (int i = tid; i < 1152; i += 256) d1[i] = s1[i];
        const uint4* s2 = (const uint4*)w2t_g;
        uint4* d2 = (uint4*)W2t;
        for (int i = tid; i < 1088; i += 256) d2[i] = s2[i];
    }
    if (tid < 128) b1s[tid] = b1[tid];
    __syncthreads();

    const int w  = tid >> 6;
    const int l  = tid & 63;
    const int ln = l & 15;
    const int q  = l >> 4;
    const int m0 = blockIdx.x * 64 + w * 16;

    // A-frags straight from global (dense 16B/lane)
    int arow = m0 + ln; if (arow > n - 1) arow = n - 1;
    const unsigned short* arp = Ab + (size_t)arow * 64 + q * 8;
    bf16x8 a0 = *(const bf16x8*)(arp);
    bf16x8 a1 = *(const bf16x8*)(arp + 32);

    // norm_src for this lane's 4 output rows
    float ns[4];
    #pragma unroll
    for (int r = 0; r < 4; ++r) {
        int node = m0 + q * 4 + r;
        ns[r] = norm[node < n ? node : n - 1];
    }

    // ---- layer 1: 8 col-tiles x (2 MFMA, K=64) ----
    #pragma unroll
    for (int c = 0; c < 8; ++c) {
        const unsigned short* bp = W1t + (c * 16 + ln) * 72 + q * 8;
        bf16x8 b0 = *(const bf16x8*)(bp);
        bf16x8 bk = *(const bf16x8*)(bp + 32);
        f32x4 acc = {0.f, 0.f, 0.f, 0.f};
        acc = __builtin_amdgcn_mfma_f32_16x16x32_bf16(a0, b0, acc, 0, 0, 0);
        acc = __builtin_amdgcn_mfma_f32_16x16x32_bf16(a1, bk, acc, 0, 0, 0);
        int col = c * 16 + ln;
        float bb = b1s[col];
        #pragma unroll
        for (int r = 0; r < 4; ++r) {
            float v = acc[r] + bb;
            v = v > 0.f ? v : 0.f;
            Hs[(w * 16 + q * 4 + r) * 136 + col] = f2bf(v * ns[r]);
        }
    }
    __syncthreads();

    // ---- layer 2: 4 col-tiles x (4 MFMA, K=128) ----
    const unsigned short* hp = Hs + (size_t)(w * 16 + ln) * 136 + q * 8;
    bf16x8 h0 = *(const bf16x8*)(hp);
    bf16x8 h1 = *(const bf16x8*)(hp + 32);
    bf16x8 h2 = *(const bf16x8*)(hp + 64);
    bf16x8 h3 = *(const bf16x8*)(hp + 96);
    #pragma unroll
    for (int c = 0; c < 4; ++c) {
        const unsigned short* bp = W2t + (c * 16 + ln) * 136 + q * 8;
        f32x4 acc = {0.f, 0.f, 0.f, 0.f};
        acc = __builtin_amdgcn_mfma_f32_16x16x32_bf16(h0, *(const bf16x8*)(bp),      acc, 0, 0, 0);
        acc = __builtin_amdgcn_mfma_f32_16x16x32_bf16(h1, *(const bf16x8*)(bp + 32), acc, 0, 0, 0);
        acc = __builtin_amdgcn_mfma_f32_16x16x32_bf16(h2, *(const bf16x8*)(bp + 64), acc, 0, 0, 0);
        acc = __builtin_amdgcn_mfma_f32_16x16x32_bf16(h3, *(const bf16x8*)(bp + 96), acc, 0, 0, 0);
        #pragma unroll
        for (int r = 0; r < 4; ++r) {
            int node = m0 + q * 4 + r;
            if (node < n)
                y2b[(size_t)node * 64 + c * 16 + ln] = f2bf(acc[r]);
        }
    }
}

extern "C" void kernel_launch(void* const* d_in, const int* in_sizes, int n_in,
                              void* d_out, int out_size, void* d_ws, size_t ws_size,
                              hipStream_t stream) {
    const float* h   = (const float*)d_in[0];
    const int*   src = (const int*)d_in[1];
    const int*   dst = (const int*)d_in[2];
    const float* W1  = (const float*)d_in[3];
    const float* b1  = (const float*)d_in[4];
    const float* W2  = (const float*)d_in[5];
    const float* b2  = (const float*)d_in[6];
    float* out = (float*)d_out;

    const int n = in_sizes[0] / 64;
    const int E = in_sizes[1];
    const int nb = (n + 127) >> 7;

    char* p = (char*)d_ws;
    auto alloc = [&](size_t bytes) {
        void* r = (void*)p;
        p += (bytes + 255) & ~(size_t)255;
        return r;
    };
    float* norm_src      = (float*)alloc((size_t)n * 4);
    float* norm_dst      = (float*)alloc((size_t)n * 4);
    int* deg2            = (int*)alloc((size_t)2 * n * 4);
    int* deg_out = deg2;
    int* cur_in  = deg2 + n;
    unsigned short* slot = (unsigned short*)alloc((size_t)n * SLOT * 2);
    unsigned short* xb   = (unsigned short*)alloc((size_t)n * 64 * 2);
    unsigned short* agg1b= (unsigned short*)alloc((size_t)n * 64 * 2);
    unsigned short* y2b  = (unsigned short*)alloc((size_t)n * 64 * 2);
    unsigned short* w1t_g= (unsigned short*)alloc((size_t)128 * 72 * 2);
    unsigned short* w2t_g= (unsigned short*)alloc((size_t)64 * 136 * 2);

    hipMemsetAsync(deg2, 0, 2 * (size_t)n * sizeof(int), stream);

    int sb = (E + 1023) / 1024;   // 4 edges/thread
    scatter_edges<<<sb + 1, 256, 0, stream>>>(src, dst, deg_out, cur_in, slot,
                                              E, W1, W2, w1t_g, w2t_g);
    prep2<<<nb, 256, 0, stream>>>(h, deg_out, cur_in, norm_src, norm_dst, xb, n);

    int gb = (n + 3) / 4;
    gather24<<<gb, 256, 0, stream>>>(xb, slot, cur_in, norm_dst, nullptr,
                                     (void*)agg1b, 1, n);

    int tb = (n + 63) / 64;
    gemm12<<<tb, 256, 0, stream>>>(agg1b, w1t_g, b1, norm_src, w2t_g, y2b, n);

    gather24<<<gb, 256, 0, stream>>>(y2b, slot, cur_in, norm_dst, b2,
                                     (void*)out, 0, n);
}

// Round 4
// 175.520 us; speedup vs baseline: 1.2455x; 1.2455x over previous
//
#include <hip/hip_runtime.h>

// F0=64, F1=128, F2=64. n<=65536, buckets of 128 nodes, slotted CSR with
// fixed bucket capacity CAP (no hist/scan passes).
// Pipeline: memset(cnt) -> place_direct (256 blocks, 2 edge passes; last
//           block pre-converts W1/W2) -> prep(srcdeg+scale+bucketsort) ->
//           gather24(xb->agg1b bf16) -> gemm12_mfma (both layers, H in LDS)
//           -> gather24(y2b->out f32,+b2)

#define NBMAX 512
#define CAPLOG 12
#define CAP (1 << CAPLOG)

typedef __attribute__((ext_vector_type(8))) short bf16x8;
typedef __attribute__((ext_vector_type(4))) float f32x4;

__device__ inline unsigned short f2bf(float f) {
    unsigned int u = __float_as_uint(f);
    unsigned int r = (u + 0x7FFFu + ((u >> 16) & 1u)) >> 16;  // RNE
    return (unsigned short)r;
}
__device__ inline float bf2f_lo(unsigned int u) { return __uint_as_float(u << 16); }
__device__ inline float bf2f_hi(unsigned int u) { return __uint_as_float(u & 0xFFFF0000u); }

// One pass over edges: per-block LDS hist -> one global reservation atomic per
// (block,bucket) -> LDS-cursor scatter into slotted bucket arrays.
// src entry: 1B local id. dst entry: (dst&127)<<25 | src.
// LAST block instead pre-converts W1/W2 into padded bf16 images so gemm12
// stages with pure vec copies.
__global__ __launch_bounds__(256) void place_direct(const int* __restrict__ src,
        const int* __restrict__ dst, int* __restrict__ cnt_s, int* __restrict__ cnt_d,
        unsigned char* __restrict__ ss, unsigned int* __restrict__ sd,
        int n_edges, int nb,
        const float* __restrict__ W1, const float* __restrict__ W2,
        unsigned short* __restrict__ w1t_g, unsigned short* __restrict__ w2t_g) {
    if (blockIdx.x == gridDim.x - 1) {
        for (int i = threadIdx.x; i < 8192; i += 256) {   // W1[64][128] -> [n][k] pad 72
            int k = i >> 7, nn = i & 127;
            w1t_g[nn * 72 + k] = f2bf(W1[i]);
        }
        for (int i = threadIdx.x; i < 8192; i += 256) {   // W2[128][64] -> [n][k] pad 136
            int k = i >> 6, nn = i & 63;
            w2t_g[nn * 136 + k] = f2bf(W2[i]);
        }
        return;
    }
    __shared__ int hs[NBMAX], hd[NBMAX], bs[NBMAX], bd[NBMAX];
    for (int i = threadIdx.x; i < nb; i += 256) { hs[i] = 0; hd[i] = 0; }
    __syncthreads();
    const int nact = gridDim.x - 1;
    int chunk = (n_edges + nact - 1) / nact;
    int e0 = blockIdx.x * chunk;
    int e1 = e0 + chunk; if (e1 > n_edges) e1 = n_edges;
    for (int e = e0 + (int)threadIdx.x; e < e1; e += 256) {
        atomicAdd(&hs[src[e] >> 7], 1);
        atomicAdd(&hd[dst[e] >> 7], 1);
    }
    __syncthreads();
    for (int i = threadIdx.x; i < nb; i += 256) {
        int v = hs[i]; bs[i] = v ? atomicAdd(&cnt_s[i], v) : 0; hs[i] = 0;
        v = hd[i];     bd[i] = v ? atomicAdd(&cnt_d[i], v) : 0; hd[i] = 0;
    }
    __syncthreads();
    for (int e = e0 + (int)threadIdx.x; e < e1; e += 256) {
        int s = src[e], d = dst[e];
        int sb = s >> 7, db = d >> 7;
        int ps = bs[sb] + atomicAdd(&hs[sb], 1);
        ss[((size_t)sb << CAPLOG) + ps] = (unsigned char)(s & 127);
        int pd = bd[db] + atomicAdd(&hd[db], 1);
        sd[((size_t)db << CAPLOG) + pd] = ((unsigned int)(d & 127) << 25) | (unsigned int)s;
    }
}

// One block per bucket b:
//  phase 1 (src side): count ss local ids -> norm_src; xb = bf16(h * norm).
//  phase 2 (dst side): 128-bin count of sd -> scan -> node_rng + counting-sorted
//                      srt (u16 src ids) + norm_dst.
__global__ __launch_bounds__(256) void prep(const float* __restrict__ h,
        const unsigned char* __restrict__ ss, const int* __restrict__ cnt_s,
        const unsigned int* __restrict__ sd, const int* __restrict__ cnt_d,
        float* __restrict__ norm_src, unsigned short* __restrict__ xb,
        int2* __restrict__ node_rng, unsigned short* __restrict__ srt,
        float* __restrict__ norm_dst, int n) {
    __shared__ int cnt[128], cur[128];
    __shared__ float nrm[128];
    __shared__ int w0tot;
    const int b = blockIdx.x;
    const int tid = threadIdx.x;

    // ---- phase 1: src degree + scale/cast ----
    if (tid < 128) cnt[tid] = 0;
    __syncthreads();
    {
        int used = cnt_s[b];
        const unsigned char* p = ss + ((size_t)b << CAPLOG);
        for (int i = tid; i < used; i += 256) atomicAdd(&cnt[p[i]], 1);
    }
    __syncthreads();
    if (tid < 128) {
        int c = cnt[tid]; if (c < 1) c = 1;
        float s = 1.0f / sqrtf((float)c);
        nrm[tid] = s;
        int node = (b << 7) + tid;
        if (node < n) norm_src[node] = s;
    }
    __syncthreads();
    {
        int base = b << 7;
        for (int t = tid; t < 128 * 16; t += 256) {
            int r = t >> 4, c4 = (t & 15) << 2;
            int node = base + r;
            if (node < n) {
                float s = nrm[r];
                float4 v = *(const float4*)(h + (size_t)node * 64 + c4);
                ushort4 o;
                o.x = f2bf(v.x * s); o.y = f2bf(v.y * s);
                o.z = f2bf(v.z * s); o.w = f2bf(v.w * s);
                *(ushort4*)(xb + (size_t)node * 64 + c4) = o;
            }
        }
    }
    __syncthreads();

    // ---- phase 2: dst bucket counting sort ----
    if (tid < 128) cnt[tid] = 0;
    __syncthreads();
    int used = cnt_d[b];
    const unsigned int* p = sd + ((size_t)b << CAPLOG);
    for (int i = tid; i < used; i += 256) atomicAdd(&cnt[p[i] >> 25], 1);
    __syncthreads();
    int lane = tid & 63, wid = tid >> 6;
    int v = (tid < 128) ? cnt[tid] : 0;
    int incl = v;
    #pragma unroll
    for (int d = 1; d < 64; d <<= 1) {
        int t = __shfl_up(incl, d, 64);
        if (lane >= d) incl += t;
    }
    if (tid == 63) w0tot = incl;
    __syncthreads();
    if (tid < 128) {
        int excl = incl - v + (wid == 1 ? w0tot : 0);
        cur[tid] = excl;
        int node = (b << 7) + tid;
        if (node < n) {
            int base = b << CAPLOG;
            node_rng[node] = make_int2(base + excl, base + excl + v);
            int c = v; if (c < 1) c = 1;
            norm_dst[node] = 1.0f / sqrtf((float)c);
        }
    }
    __syncthreads();
    for (int i = tid; i < used; i += 256) {
        unsigned int e = p[i];
        int l = (int)(e >> 25);
        int pos = atomicAdd(&cur[l], 1);
        srt[((size_t)b << CAPLOG) + pos] = (unsigned short)(e & 0xFFFFu);
    }
}

// One wave per dst node. 8 lanes x bf16x8 (16B dwordx4) cover the 64-wide row;
// 8 lane-groups x unroll 3 -> 24 edges in flight per round.
// f32 accumulate, 3-level shfl_xor reduce; writes bf16 row (mode 1) or f32
// row +bias (mode 0).
__global__ __launch_bounds__(256) void gather24(const unsigned short* __restrict__ xb,
        const unsigned short* __restrict__ srt, const int2* __restrict__ node_rng,
        const float* __restrict__ nrm, const float* __restrict__ bias,
        void* __restrict__ outp, int write_bf, int n_nodes) {
    int node = blockIdx.x * 4 + (threadIdx.x >> 6);
    if (node >= n_nodes) return;
    int lane = threadIdx.x & 63;
    int g  = lane >> 3;         // edge slot 0..7
    int c8 = (lane & 7) * 8;    // column base
    int2 rng = node_rng[node];
    int a0 = rng.x, a1 = rng.y;
    float acc[8];
    #pragma unroll
    for (int j = 0; j < 8; ++j) acc[j] = 0.f;
    for (int base = a0; base < a1; base += 24) {
        #pragma unroll
        for (int u = 0; u < 3; ++u) {
            int ei = base + u * 8 + g;
            int idx = ei < a1 ? ei : a1 - 1;
            float msk = ei < a1 ? 1.0f : 0.0f;
            int s = srt[idx];
            const uint4 v = *(const uint4*)(xb + (size_t)s * 64 + c8);
            acc[0] = fmaf(bf2f_lo(v.x), msk, acc[0]);
            acc[1] = fmaf(bf2f_hi(v.x), msk, acc[1]);
            acc[2] = fmaf(bf2f_lo(v.y), msk, acc[2]);
            acc[3] = fmaf(bf2f_hi(v.y), msk, acc[3]);
            acc[4] = fmaf(bf2f_lo(v.z), msk, acc[4]);
            acc[5] = fmaf(bf2f_hi(v.z), msk, acc[5]);
            acc[6] = fmaf(bf2f_lo(v.w), msk, acc[6]);
            acc[7] = fmaf(bf2f_hi(v.w), msk, acc[7]);
        }
    }
    #pragma unroll
    for (int off = 8; off < 64; off <<= 1) {
        #pragma unroll
        for (int j = 0; j < 8; ++j) acc[j] += __shfl_xor(acc[j], off, 64);
    }
    if (g == 0) {
        float s = nrm[node];
        float r[8];
        #pragma unroll
        for (int j = 0; j < 8; ++j) r[j] = acc[j] * s;
        if (write_bf) {
            unsigned short rb[8];
            #pragma unroll
            for (int j = 0; j < 8; ++j) rb[j] = f2bf(r[j]);
            unsigned short* o = (unsigned short*)outp + (size_t)node * 64 + c8;
            *(ushort4*)(o)     = make_ushort4(rb[0], rb[1], rb[2], rb[3]);
            *(ushort4*)(o + 4) = make_ushort4(rb[4], rb[5], rb[6], rb[7]);
        } else {
            if (bias) {
                #pragma unroll
                for (int j = 0; j < 8; ++j) r[j] += bias[c8 + j];
            }
            float* o = (float*)outp + (size_t)node * 64 + c8;
            *(float4*)(o)     = make_float4(r[0], r[1], r[2], r[3]);
            *(float4*)(o + 4) = make_float4(r[4], r[5], r[6], r[7]);
        }
    }
}

// MFMA fused both layers per 64-node tile. 4 waves, wave w owns nodes
// m0+w*16..+15.  Layouts (verified per guide m89/m91/m120):
//   A-frag  lane l: A[m = l&15][k = (l>>4)*8 + j]     (bf16x8, 16B/lane)
//   B-frag  lane l: B[k = (l>>4)*8 + j][n = l&15]
//   C/D     lane l reg r: D[m = (l>>4)*4 + r][n = l&15]
// W1t/W2t images are pre-built in global (place_direct spare block); staging
// here is pure uint4 LDS copy. H tile (layer-1 out) goes through LDS
// (C-layout -> A-layout transform).
__global__ __launch_bounds__(256) void gemm12(const unsigned short* __restrict__ Ab,
        const unsigned short* __restrict__ w1t_g, const float* __restrict__ b1,
        const float* __restrict__ norm, const unsigned short* __restrict__ w2t_g,
        unsigned short* __restrict__ y2b, int n) {
    __shared__ __align__(16) unsigned short W1t[128 * 72];   // [n][k] pad 72 (2-way, free)
    __shared__ __align__(16) unsigned short W2t[64 * 136];   // [n][k] pad 136
    __shared__ __align__(16) unsigned short Hs[64 * 136];    // [m][k] pad 136
    __shared__ float b1s[128];
    const int tid = threadIdx.x;

    {   // stage pre-built weight images: 1152 + 1088 uint4
        const uint4* s1 = (const uint4*)w1t_g;
        uint4* d1 = (uint4*)W1t;
        for (int i = tid; i < 1152; i += 256) d1[i] = s1[i];
        const uint4* s2 = (const uint4*)w2t_g;
        uint4* d2 = (uint4*)W2t;
        for (int i = tid; i < 1088; i += 256) d2[i] = s2[i];
    }
    if (tid < 128) b1s[tid] = b1[tid];
    __syncthreads();

    const int w  = tid >> 6;
    const int l  = tid & 63;
    const int ln = l & 15;
    const int q  = l >> 4;
    const int m0 = blockIdx.x * 64 + w * 16;

    // A-frags straight from global (dense 16B/lane)
    int arow = m0 + ln; if (arow > n - 1) arow = n - 1;
    const unsigned short* arp = Ab + (size_t)arow * 64 + q * 8;
    bf16x8 a0 = *(const bf16x8*)(arp);
    bf16x8 a1 = *(const bf16x8*)(arp + 32);

    // norm_src for this lane's 4 output rows
    float ns[4];
    #pragma unroll
    for (int r = 0; r < 4; ++r) {
        int node = m0 + q * 4 + r;
        ns[r] = norm[node < n ? node : n - 1];
    }

    // ---- layer 1: 8 col-tiles x (2 MFMA, K=64) ----
    #pragma unroll
    for (int c = 0; c < 8; ++c) {
        const unsigned short* bp = W1t + (c * 16 + ln) * 72 + q * 8;
        bf16x8 b0 = *(const bf16x8*)(bp);
        bf16x8 bk = *(const bf16x8*)(bp + 32);
        f32x4 acc = {0.f, 0.f, 0.f, 0.f};
        acc = __builtin_amdgcn_mfma_f32_16x16x32_bf16(a0, b0, acc, 0, 0, 0);
        acc = __builtin_amdgcn_mfma_f32_16x16x32_bf16(a1, bk, acc, 0, 0, 0);
        int col = c * 16 + ln;
        float bb = b1s[col];
        #pragma unroll
        for (int r = 0; r < 4; ++r) {
            float v = acc[r] + bb;
            v = v > 0.f ? v : 0.f;
            Hs[(w * 16 + q * 4 + r) * 136 + col] = f2bf(v * ns[r]);
        }
    }
    __syncthreads();

    // ---- layer 2: 4 col-tiles x (4 MFMA, K=128) ----
    const unsigned short* hp = Hs + (size_t)(w * 16 + ln) * 136 + q * 8;
    bf16x8 h0 = *(const bf16x8*)(hp);
    bf16x8 h1 = *(const bf16x8*)(hp + 32);
    bf16x8 h2 = *(const bf16x8*)(hp + 64);
    bf16x8 h3 = *(const bf16x8*)(hp + 96);
    #pragma unroll
    for (int c = 0; c < 4; ++c) {
        const unsigned short* bp = W2t + (c * 16 + ln) * 136 + q * 8;
        f32x4 acc = {0.f, 0.f, 0.f, 0.f};
        acc = __builtin_amdgcn_mfma_f32_16x16x32_bf16(h0, *(const bf16x8*)(bp),      acc, 0, 0, 0);
        acc = __builtin_amdgcn_mfma_f32_16x16x32_bf16(h1, *(const bf16x8*)(bp + 32), acc, 0, 0, 0);
        acc = __builtin_amdgcn_mfma_f32_16x16x32_bf16(h2, *(const bf16x8*)(bp + 64), acc, 0, 0, 0);
        acc = __builtin_amdgcn_mfma_f32_16x16x32_bf16(h3, *(const bf16x8*)(bp + 96), acc, 0, 0, 0);
        #pragma unroll
        for (int r = 0; r < 4; ++r) {
            int node = m0 + q * 4 + r;
            if (node < n)
                y2b[(size_t)node * 64 + c * 16 + ln] = f2bf(acc[r]);
        }
    }
}

extern "C" void kernel_launch(void* const* d_in, const int* in_sizes, int n_in,
                              void* d_out, int out_size, void* d_ws, size_t ws_size,
                              hipStream_t stream) {
    const float* h   = (const float*)d_in[0];
    const int*   src = (const int*)d_in[1];
    const int*   dst = (const int*)d_in[2];
    const float* W1  = (const float*)d_in[3];
    const float* b1  = (const float*)d_in[4];
    const float* W2  = (const float*)d_in[5];
    const float* b2  = (const float*)d_in[6];
    float* out = (float*)d_out;

    const int n = in_sizes[0] / 64;
    const int E = in_sizes[1];
    const int nb = (n + 127) >> 7;

    char* p = (char*)d_ws;
    auto alloc = [&](size_t bytes) {
        void* r = (void*)p;
        p += (bytes + 255) & ~(size_t)255;
        return r;
    };
    float* norm_src      = (float*)alloc((size_t)n * 4);
    float* norm_dst      = (float*)alloc((size_t)n * 4);
    int2* node_rng       = (int2*)alloc((size_t)n * 8);
    int* cnt2            = (int*)alloc((size_t)2 * nb * 4);
    int* cnt_s = cnt2;
    int* cnt_d = cnt2 + nb;
    unsigned int* sd     = (unsigned int*)alloc((size_t)nb * CAP * 4);
    unsigned short* xb   = (unsigned short*)alloc((size_t)n * 64 * 2);
    unsigned short* agg1b= (unsigned short*)alloc((size_t)n * 64 * 2);
    unsigned short* y2b  = (unsigned short*)alloc((size_t)n * 64 * 2);
    unsigned short* srt  = (unsigned short*)alloc((size_t)nb * CAP * 2);
    unsigned char* ssb   = (unsigned char*)alloc((size_t)nb * CAP);
    unsigned short* w1t_g= (unsigned short*)alloc((size_t)128 * 72 * 2);
    unsigned short* w2t_g= (unsigned short*)alloc((size_t)64 * 136 * 2);

    hipMemsetAsync(cnt2, 0, 2 * (size_t)nb * sizeof(int), stream);

    place_direct<<<257, 256, 0, stream>>>(src, dst, cnt_s, cnt_d, ssb, sd,
                                          E, nb, W1, W2, w1t_g, w2t_g);
    prep<<<nb, 256, 0, stream>>>(h, ssb, cnt_s, sd, cnt_d, norm_src, xb,
                                 node_rng, srt, norm_dst, n);

    int gb = (n + 3) / 4;
    gather24<<<gb, 256, 0, stream>>>(xb, srt, node_rng, norm_dst, nullptr,
                                     (void*)agg1b, 1, n);

    int tb = (n + 63) / 64;
    gemm12<<<tb, 256, 0, stream>>>(agg1b, w1t_g, b1, norm_src, w2t_g, y2b, n);

    gather24<<<gb, 256, 0, stream>>>(y2b, srt, node_rng, norm_dst, b2,
                                     (void*)out, 0, n);
}

// Round 5
// 173.338 us; speedup vs baseline: 1.2611x; 1.0126x over previous
//
#include <hip/hip_runtime.h>

// F0=64, F1=128, F2=64. n<=65536, buckets of 128 nodes, slotted CSR with
// fixed bucket capacity CAP. Deterministic binning (NO global atomics):
//   hist_edges:    per-block LDS hist -> hist[block][bucket] (private rows)
//   scan_hist:     per-bucket exclusive scan over blocks -> offs[block][bucket]
//                  + per-bucket totals (cnt_s/cnt_d). No memset needed.
//   scatter_binned: re-read edges (L3-warm), LDS cursors from offs, scatter
//                  ss/sd. Zero contended atomics anywhere in the pipeline.
// Then: prep(srcdeg+scale+bucketsort) -> gather24(xb->agg1b bf16) ->
//       gemm12_mfma (both layers, H in LDS) -> gather24(y2b->out f32,+b2)

#define NBMAX 512
#define CAPLOG 12
#define CAP (1 << CAPLOG)
#define NB_BIN 256              // binning blocks; K1/K3 chunking must match

typedef __attribute__((ext_vector_type(8))) short bf16x8;
typedef __attribute__((ext_vector_type(4))) float f32x4;

__device__ inline unsigned short f2bf(float f) {
    unsigned int u = __float_as_uint(f);
    unsigned int r = (u + 0x7FFFu + ((u >> 16) & 1u)) >> 16;  // RNE
    return (unsigned short)r;
}
__device__ inline float bf2f_lo(unsigned int u) { return __uint_as_float(u << 16); }
__device__ inline float bf2f_hi(unsigned int u) { return __uint_as_float(u & 0xFFFF0000u); }

// K1: one streaming pass over edges -> per-block private hist rows.
// hist layout: hist[side(0=s,1=d)][block][bucket], row stride NBMAX.
// LAST block instead pre-converts W1/W2 into padded bf16 images.
__global__ __launch_bounds__(256) void hist_edges(const int* __restrict__ src,
        const int* __restrict__ dst, int* __restrict__ hist, int n_edges, int nb,
        const float* __restrict__ W1, const float* __restrict__ W2,
        unsigned short* __restrict__ w1t_g, unsigned short* __restrict__ w2t_g) {
    if (blockIdx.x == gridDim.x - 1) {
        for (int i = threadIdx.x; i < 8192; i += 256) {   // W1[64][128] -> [n][k] pad 72
            int k = i >> 7, nn = i & 127;
            w1t_g[nn * 72 + k] = f2bf(W1[i]);
        }
        for (int i = threadIdx.x; i < 8192; i += 256) {   // W2[128][64] -> [n][k] pad 136
            int k = i >> 6, nn = i & 63;
            w2t_g[nn * 136 + k] = f2bf(W2[i]);
        }
        return;
    }
    __shared__ int hs[NBMAX], hd[NBMAX];
    for (int i = threadIdx.x; i < nb; i += 256) { hs[i] = 0; hd[i] = 0; }
    __syncthreads();
    int chunk = (n_edges + NB_BIN - 1) / NB_BIN;
    int e0 = blockIdx.x * chunk;
    int e1 = e0 + chunk; if (e1 > n_edges) e1 = n_edges;
    for (int e = e0 + (int)threadIdx.x; e < e1; e += 256) {
        atomicAdd(&hs[src[e] >> 7], 1);
        atomicAdd(&hd[dst[e] >> 7], 1);
    }
    __syncthreads();
    int* rs = hist + (size_t)blockIdx.x * NBMAX;
    int* rd = hist + (size_t)(NB_BIN + blockIdx.x) * NBMAX;
    for (int i = threadIdx.x; i < nb; i += 256) { rs[i] = hs[i]; rd[i] = hd[i]; }
}

// K2: block j scans 256 per-block counts of one (side,bucket) instance.
// offs[side][block][bucket] = exclusive prefix; also writes bucket totals.
__global__ __launch_bounds__(256) void scan_hist(const int* __restrict__ hist,
        int* __restrict__ offs, int* __restrict__ cnt_s, int* __restrict__ cnt_d,
        int nb) {
    __shared__ int wtot[4];
    int j = blockIdx.x;
    int side = j >= nb ? 1 : 0;
    int bucket = j - side * nb;
    const int tid = threadIdx.x;
    size_t idx = (size_t)(side * NB_BIN + tid) * NBMAX + bucket;
    int v = hist[idx];
    int lane = tid & 63, wid = tid >> 6;
    int incl = v;
    #pragma unroll
    for (int d = 1; d < 64; d <<= 1) {
        int t = __shfl_up(incl, d, 64);
        if (lane >= d) incl += t;
    }
    if (lane == 63) wtot[wid] = incl;
    __syncthreads();
    int pre = 0;
    #pragma unroll
    for (int k = 0; k < 3; ++k) if (k < wid) pre += wtot[k];
    int excl = pre + incl - v;
    offs[idx] = excl;
    if (tid == 255) {
        int tot = excl + v;
        if (side) cnt_d[bucket] = tot; else cnt_s[bucket] = tot;
    }
}

// K3: re-read edges (same chunking as K1), LDS cursors seeded from offs,
// scatter into slotted bucket arrays. LDS atomics only.
// src entry: 1B local id. dst entry: (dst&127)<<25 | src.
__global__ __launch_bounds__(256) void scatter_binned(const int* __restrict__ src,
        const int* __restrict__ dst, const int* __restrict__ offs,
        unsigned char* __restrict__ ss, unsigned int* __restrict__ sd,
        int n_edges, int nb) {
    __shared__ int cs[NBMAX], cd[NBMAX];
    for (int i = threadIdx.x; i < nb; i += 256) {
        cs[i] = offs[(size_t)blockIdx.x * NBMAX + i];
        cd[i] = offs[(size_t)(NB_BIN + blockIdx.x) * NBMAX + i];
    }
    __syncthreads();
    int chunk = (n_edges + NB_BIN - 1) / NB_BIN;
    int e0 = blockIdx.x * chunk;
    int e1 = e0 + chunk; if (e1 > n_edges) e1 = n_edges;
    for (int e = e0 + (int)threadIdx.x; e < e1; e += 256) {
        int s = src[e], d = dst[e];
        int sb = s >> 7, db = d >> 7;
        int ps = atomicAdd(&cs[sb], 1);
        ss[((size_t)sb << CAPLOG) + ps] = (unsigned char)(s & 127);
        int pd = atomicAdd(&cd[db], 1);
        sd[((size_t)db << CAPLOG) + pd] = ((unsigned int)(d & 127) << 25) | (unsigned int)s;
    }
}

// One block per bucket b:
//  phase 1 (src side): count ss local ids -> norm_src; xb = bf16(h * norm).
//  phase 2 (dst side): 128-bin count of sd -> scan -> node_rng + counting-sorted
//                      srt (u16 src ids) + norm_dst.
__global__ __launch_bounds__(256) void prep(const float* __restrict__ h,
        const unsigned char* __restrict__ ss, const int* __restrict__ cnt_s,
        const unsigned int* __restrict__ sd, const int* __restrict__ cnt_d,
        float* __restrict__ norm_src, unsigned short* __restrict__ xb,
        int2* __restrict__ node_rng, unsigned short* __restrict__ srt,
        float* __restrict__ norm_dst, int n) {
    __shared__ int cnt[128], cur[128];
    __shared__ float nrm[128];
    __shared__ int w0tot;
    const int b = blockIdx.x;
    const int tid = threadIdx.x;

    // ---- phase 1: src degree + scale/cast ----
    if (tid < 128) cnt[tid] = 0;
    __syncthreads();
    {
        int used = cnt_s[b];
        const unsigned char* p = ss + ((size_t)b << CAPLOG);
        for (int i = tid; i < used; i += 256) atomicAdd(&cnt[p[i]], 1);
    }
    __syncthreads();
    if (tid < 128) {
        int c = cnt[tid]; if (c < 1) c = 1;
        float s = 1.0f / sqrtf((float)c);
        nrm[tid] = s;
        int node = (b << 7) + tid;
        if (node < n) norm_src[node] = s;
    }
    __syncthreads();
    {
        int base = b << 7;
        for (int t = tid; t < 128 * 16; t += 256) {
            int r = t >> 4, c4 = (t & 15) << 2;
            int node = base + r;
            if (node < n) {
                float s = nrm[r];
                float4 v = *(const float4*)(h + (size_t)node * 64 + c4);
                ushort4 o;
                o.x = f2bf(v.x * s); o.y = f2bf(v.y * s);
                o.z = f2bf(v.z * s); o.w = f2bf(v.w * s);
                *(ushort4*)(xb + (size_t)node * 64 + c4) = o;
            }
        }
    }
    __syncthreads();

    // ---- phase 2: dst bucket counting sort ----
    if (tid < 128) cnt[tid] = 0;
    __syncthreads();
    int used = cnt_d[b];
    const unsigned int* p = sd + ((size_t)b << CAPLOG);
    for (int i = tid; i < used; i += 256) atomicAdd(&cnt[p[i] >> 25], 1);
    __syncthreads();
    int lane = tid & 63, wid = tid >> 6;
    int v = (tid < 128) ? cnt[tid] : 0;
    int incl = v;
    #pragma unroll
    for (int d = 1; d < 64; d <<= 1) {
        int t = __shfl_up(incl, d, 64);
        if (lane >= d) incl += t;
    }
    if (tid == 63) w0tot = incl;
    __syncthreads();
    if (tid < 128) {
        int excl = incl - v + (wid == 1 ? w0tot : 0);
        cur[tid] = excl;
        int node = (b << 7) + tid;
        if (node < n) {
            int base = b << CAPLOG;
            node_rng[node] = make_int2(base + excl, base + excl + v);
            int c = v; if (c < 1) c = 1;
            norm_dst[node] = 1.0f / sqrtf((float)c);
        }
    }
    __syncthreads();
    for (int i = tid; i < used; i += 256) {
        unsigned int e = p[i];
        int l = (int)(e >> 25);
        int pos = atomicAdd(&cur[l], 1);
        srt[((size_t)b << CAPLOG) + pos] = (unsigned short)(e & 0xFFFFu);
    }
}

// One wave per dst node. 8 lanes x bf16x8 (16B dwordx4) cover the 64-wide row;
// 8 lane-groups x unroll 3 -> 24 edges in flight per round.
// f32 accumulate, 3-level shfl_xor reduce; writes bf16 row (mode 1) or f32
// row +bias (mode 0).
__global__ __launch_bounds__(256) void gather24(const unsigned short* __restrict__ xb,
        const unsigned short* __restrict__ srt, const int2* __restrict__ node_rng,
        const float* __restrict__ nrm, const float* __restrict__ bias,
        void* __restrict__ outp, int write_bf, int n_nodes) {
    int node = blockIdx.x * 4 + (threadIdx.x >> 6);
    if (node >= n_nodes) return;
    int lane = threadIdx.x & 63;
    int g  = lane >> 3;         // edge slot 0..7
    int c8 = (lane & 7) * 8;    // column base
    int2 rng = node_rng[node];
    int a0 = rng.x, a1 = rng.y;
    float acc[8];
    #pragma unroll
    for (int j = 0; j < 8; ++j) acc[j] = 0.f;
    for (int base = a0; base < a1; base += 24) {
        #pragma unroll
        for (int u = 0; u < 3; ++u) {
            int ei = base + u * 8 + g;
            int idx = ei < a1 ? ei : a1 - 1;
            float msk = ei < a1 ? 1.0f : 0.0f;
            int s = srt[idx];
            const uint4 v = *(const uint4*)(xb + (size_t)s * 64 + c8);
            acc[0] = fmaf(bf2f_lo(v.x), msk, acc[0]);
            acc[1] = fmaf(bf2f_hi(v.x), msk, acc[1]);
            acc[2] = fmaf(bf2f_lo(v.y), msk, acc[2]);
            acc[3] = fmaf(bf2f_hi(v.y), msk, acc[3]);
            acc[4] = fmaf(bf2f_lo(v.z), msk, acc[4]);
            acc[5] = fmaf(bf2f_hi(v.z), msk, acc[5]);
            acc[6] = fmaf(bf2f_lo(v.w), msk, acc[6]);
            acc[7] = fmaf(bf2f_hi(v.w), msk, acc[7]);
        }
    }
    #pragma unroll
    for (int off = 8; off < 64; off <<= 1) {
        #pragma unroll
        for (int j = 0; j < 8; ++j) acc[j] += __shfl_xor(acc[j], off, 64);
    }
    if (g == 0) {
        float s = nrm[node];
        float r[8];
        #pragma unroll
        for (int j = 0; j < 8; ++j) r[j] = acc[j] * s;
        if (write_bf) {
            unsigned short rb[8];
            #pragma unroll
            for (int j = 0; j < 8; ++j) rb[j] = f2bf(r[j]);
            unsigned short* o = (unsigned short*)outp + (size_t)node * 64 + c8;
            *(ushort4*)(o)     = make_ushort4(rb[0], rb[1], rb[2], rb[3]);
            *(ushort4*)(o + 4) = make_ushort4(rb[4], rb[5], rb[6], rb[7]);
        } else {
            if (bias) {
                #pragma unroll
                for (int j = 0; j < 8; ++j) r[j] += bias[c8 + j];
            }
            float* o = (float*)outp + (size_t)node * 64 + c8;
            *(float4*)(o)     = make_float4(r[0], r[1], r[2], r[3]);
            *(float4*)(o + 4) = make_float4(r[4], r[5], r[6], r[7]);
        }
    }
}

// MFMA fused both layers per 64-node tile. 4 waves, wave w owns nodes
// m0+w*16..+15.  Layouts (verified per guide m89/m91/m120):
//   A-frag  lane l: A[m = l&15][k = (l>>4)*8 + j]     (bf16x8, 16B/lane)
//   B-frag  lane l: B[k = (l>>4)*8 + j][n = l&15]
//   C/D     lane l reg r: D[m = (l>>4)*4 + r][n = l&15]
// W1t/W2t images are pre-built in global (hist_edges spare block); staging
// here is pure uint4 LDS copy. H tile (layer-1 out) goes through LDS
// (C-layout -> A-layout transform).
__global__ __launch_bounds__(256) void gemm12(const unsigned short* __restrict__ Ab,
        const unsigned short* __restrict__ w1t_g, const float* __restrict__ b1,
        const float* __restrict__ norm, const unsigned short* __restrict__ w2t_g,
        unsigned short* __restrict__ y2b, int n) {
    __shared__ __align__(16) unsigned short W1t[128 * 72];   // [n][k] pad 72 (2-way, free)
    __shared__ __align__(16) unsigned short W2t[64 * 136];   // [n][k] pad 136
    __shared__ __align__(16) unsigned short Hs[64 * 136];    // [m][k] pad 136
    __shared__ float b1s[128];
    const int tid = threadIdx.x;

    {   // stage pre-built weight images: 1152 + 1088 uint4
        const uint4* s1 = (const uint4*)w1t_g;
        uint4* d1 = (uint4*)W1t;
        for (int i = tid; i < 1152; i += 256) d1[i] = s1[i];
        const uint4* s2 = (const uint4*)w2t_g;
        uint4* d2 = (uint4*)W2t;
        for (int i = tid; i < 1088; i += 256) d2[i] = s2[i];
    }
    if (tid < 128) b1s[tid] = b1[tid];
    __syncthreads();

    const int w  = tid >> 6;
    const int l  = tid & 63;
    const int ln = l & 15;
    const int q  = l >> 4;
    const int m0 = blockIdx.x * 64 + w * 16;

    // A-frags straight from global (dense 16B/lane)
    int arow = m0 + ln; if (arow > n - 1) arow = n - 1;
    const unsigned short* arp = Ab + (size_t)arow * 64 + q * 8;
    bf16x8 a0 = *(const bf16x8*)(arp);
    bf16x8 a1 = *(const bf16x8*)(arp + 32);

    // norm_src for this lane's 4 output rows
    float ns[4];
    #pragma unroll
    for (int r = 0; r < 4; ++r) {
        int node = m0 + q * 4 + r;
        ns[r] = norm[node < n ? node : n - 1];
    }

    // ---- layer 1: 8 col-tiles x (2 MFMA, K=64) ----
    #pragma unroll
    for (int c = 0; c < 8; ++c) {
        const unsigned short* bp = W1t + (c * 16 + ln) * 72 + q * 8;
        bf16x8 b0 = *(const bf16x8*)(bp);
        bf16x8 bk = *(const bf16x8*)(bp + 32);
        f32x4 acc = {0.f, 0.f, 0.f, 0.f};
        acc = __builtin_amdgcn_mfma_f32_16x16x32_bf16(a0, b0, acc, 0, 0, 0);
        acc = __builtin_amdgcn_mfma_f32_16x16x32_bf16(a1, bk, acc, 0, 0, 0);
        int col = c * 16 + ln;
        float bb = b1s[col];
        #pragma unroll
        for (int r = 0; r < 4; ++r) {
            float v = acc[r] + bb;
            v = v > 0.f ? v : 0.f;
            Hs[(w * 16 + q * 4 + r) * 136 + col] = f2bf(v * ns[r]);
        }
    }
    __syncthreads();

    // ---- layer 2: 4 col-tiles x (4 MFMA, K=128) ----
    const unsigned short* hp = Hs + (size_t)(w * 16 + ln) * 136 + q * 8;
    bf16x8 h0 = *(const bf16x8*)(hp);
    bf16x8 h1 = *(const bf16x8*)(hp + 32);
    bf16x8 h2 = *(const bf16x8*)(hp + 64);
    bf16x8 h3 = *(const bf16x8*)(hp + 96);
    #pragma unroll
    for (int c = 0; c < 4; ++c) {
        const unsigned short* bp = W2t + (c * 16 + ln) * 136 + q * 8;
        f32x4 acc = {0.f, 0.f, 0.f, 0.f};
        acc = __builtin_amdgcn_mfma_f32_16x16x32_bf16(h0, *(const bf16x8*)(bp),      acc, 0, 0, 0);
        acc = __builtin_amdgcn_mfma_f32_16x16x32_bf16(h1, *(const bf16x8*)(bp + 32), acc, 0, 0, 0);
        acc = __builtin_amdgcn_mfma_f32_16x16x32_bf16(h2, *(const bf16x8*)(bp + 64), acc, 0, 0, 0);
        acc = __builtin_amdgcn_mfma_f32_16x16x32_bf16(h3, *(const bf16x8*)(bp + 96), acc, 0, 0, 0);
        #pragma unroll
        for (int r = 0; r < 4; ++r) {
            int node = m0 + q * 4 + r;
            if (node < n)
                y2b[(size_t)node * 64 + c * 16 + ln] = f2bf(acc[r]);
        }
    }
}

extern "C" void kernel_launch(void* const* d_in, const int* in_sizes, int n_in,
                              void* d_out, int out_size, void* d_ws, size_t ws_size,
                              hipStream_t stream) {
    const float* h   = (const float*)d_in[0];
    const int*   src = (const int*)d_in[1];
    const int*   dst = (const int*)d_in[2];
    const float* W1  = (const float*)d_in[3];
    const float* b1  = (const float*)d_in[4];
    const float* W2  = (const float*)d_in[5];
    const float* b2  = (const float*)d_in[6];
    float* out = (float*)d_out;

    const int n = in_sizes[0] / 64;
    const int E = in_sizes[1];
    const int nb = (n + 127) >> 7;

    char* p = (char*)d_ws;
    auto alloc = [&](size_t bytes) {
        void* r = (void*)p;
        p += (bytes + 255) & ~(size_t)255;
        return r;
    };
    float* norm_src      = (float*)alloc((size_t)n * 4);
    float* norm_dst      = (float*)alloc((size_t)n * 4);
    int2* node_rng       = (int2*)alloc((size_t)n * 8);
    int* cnt_s           = (int*)alloc((size_t)nb * 4);
    int* cnt_d           = (int*)alloc((size_t)nb * 4);
    int* hist            = (int*)alloc((size_t)2 * NB_BIN * NBMAX * 4);
    int* offs            = (int*)alloc((size_t)2 * NB_BIN * NBMAX * 4);
    unsigned int* sd     = (unsigned int*)alloc((size_t)nb * CAP * 4);
    unsigned short* xb   = (unsigned short*)alloc((size_t)n * 64 * 2);
    unsigned short* agg1b= (unsigned short*)alloc((size_t)n * 64 * 2);
    unsigned short* y2b  = (unsigned short*)alloc((size_t)n * 64 * 2);
    unsigned short* srt  = (unsigned short*)alloc((size_t)nb * CAP * 2);
    unsigned char* ssb   = (unsigned char*)alloc((size_t)nb * CAP);
    unsigned short* w1t_g= (unsigned short*)alloc((size_t)128 * 72 * 2);
    unsigned short* w2t_g= (unsigned short*)alloc((size_t)64 * 136 * 2);

    hist_edges<<<NB_BIN + 1, 256, 0, stream>>>(src, dst, hist, E, nb,
                                               W1, W2, w1t_g, w2t_g);
    scan_hist<<<2 * nb, 256, 0, stream>>>(hist, offs, cnt_s, cnt_d, nb);
    scatter_binned<<<NB_BIN, 256, 0, stream>>>(src, dst, offs, ssb, sd, E, nb);
    prep<<<nb, 256, 0, stream>>>(h, ssb, cnt_s, sd, cnt_d, norm_src, xb,
                                 node_rng, srt, norm_dst, n);

    int gb = (n + 3) / 4;
    gather24<<<gb, 256, 0, stream>>>(xb, srt, node_rng, norm_dst, nullptr,
                                     (void*)agg1b, 1, n);

    int tb = (n + 63) / 64;
    gemm12<<<tb, 256, 0, stream>>>(agg1b, w1t_g, b1, norm_src, w2t_g, y2b, n);

    gather24<<<gb, 256, 0, stream>>>(y2b, srt, node_rng, norm_dst, b2,
                                     (void*)out, 0, n);
}